// Round 5
// baseline (139.446 us; speedup 1.0000x reference)
//
#include <hip/hip_runtime.h>

#define B_ 4
#define S_ 512
#define T_ 512
#define D_ 256
#define NSRC (B_ * S_)            // 2048 source rows
#define K2F 2.8853900817779268f   // 2*log2(e): exp2(x*K2F) = e^(2x)

typedef __attribute__((ext_vector_type(8))) short short8;   // 8 bf16
typedef __attribute__((ext_vector_type(4))) float f32x4;

__device__ __forceinline__ unsigned short f2bf(float f) {
    union { float f; unsigned u; } v; v.f = f;
    unsigned r = v.u + 0x7FFF + ((v.u >> 16) & 1);   // RNE
    return (unsigned short)(r >> 16);
}

// ---------------------------------------------------------------------------
// K1: prep (validated R3). blocks 0..1023: cast [src;tgt] -> abf bf16.
//     blocks 1024..1055: W -> WT bf16 via LDS 64x64 tile transpose.
//     blocks 1056..1567: prob = softmax(target @ W_prob + b_prob).
// ---------------------------------------------------------------------------
__global__ __launch_bounds__(256) void prep_kernel(
    const float* __restrict__ src, const float* __restrict__ tgt,
    const float* __restrict__ Wsrc, const float* __restrict__ Wtgt,
    const float* __restrict__ Wp, const float* __restrict__ bp,
    unsigned short* __restrict__ abf, unsigned short* __restrict__ wtb,
    float* __restrict__ out)
{
    __shared__ float tl[64 * 65];
    const int blk = blockIdx.x, tid = threadIdx.x;

    if (blk < 1024) {
        int i4 = blk * 256 + tid;
        const int half = NSRC * D_ / 4;
        const float4* in = (i4 < half) ? (const float4*)src : (const float4*)tgt;
        int j = (i4 < half) ? i4 : i4 - half;
        float4 v = in[j];
        ushort4 o;
        o.x = f2bf(v.x); o.y = f2bf(v.y); o.z = f2bf(v.z); o.w = f2bf(v.w);
        *(ushort4*)&abf[i4 * 4] = o;
    } else if (blk < 1056) {
        int wb = blk - 1024;
        int e = wb >> 4, ti = wb & 15, tr = ti >> 2, tc = ti & 3;
        int r0 = tr * 64, c0 = tc * 64;
        const float* W = e ? Wtgt : Wsrc;
        #pragma unroll
        for (int it = 0; it < 4; it++) {
            int rr = (tid >> 4) + it * 16;
            int cc = (tid & 15) * 4;
            float4 v = *(const float4*)&W[(r0 + rr) * D_ + c0 + cc];
            tl[(cc + 0) * 65 + rr] = v.x;
            tl[(cc + 1) * 65 + rr] = v.y;
            tl[(cc + 2) * 65 + rr] = v.z;
            tl[(cc + 3) * 65 + rr] = v.w;
        }
        __syncthreads();
        #pragma unroll
        for (int it = 0; it < 2; it++) {
            int jj = (tid >> 3) + it * 32;
            int kk = (tid & 7) * 8;
            ushort4 lo, hi;
            lo.x = f2bf(tl[jj * 65 + kk + 0]); lo.y = f2bf(tl[jj * 65 + kk + 1]);
            lo.z = f2bf(tl[jj * 65 + kk + 2]); lo.w = f2bf(tl[jj * 65 + kk + 3]);
            hi.x = f2bf(tl[jj * 65 + kk + 4]); hi.y = f2bf(tl[jj * 65 + kk + 5]);
            hi.z = f2bf(tl[jj * 65 + kk + 6]); hi.w = f2bf(tl[jj * 65 + kk + 7]);
            int idx = (e * 256 + c0 + jj) * D_ + r0 + kk;
            *(ushort4*)&wtb[idx] = lo;
            *(ushort4*)&wtb[idx + 4] = hi;
        }
    } else {
        int row  = (blk - 1056) * 4 + (tid >> 6);
        int lane = tid & 63;
        float p0 = 0.f, p1 = 0.f;
        #pragma unroll
        for (int i = 0; i < 4; i++) {
            int d = lane + i * 64;
            float v = tgt[row * D_ + d];
            float2 w = *(const float2*)&Wp[d * 2];
            p0 = fmaf(v, w.x, p0);
            p1 = fmaf(v, w.y, p1);
        }
        #pragma unroll
        for (int off = 32; off > 0; off >>= 1) {
            p0 += __shfl_down(p0, off, 64);
            p1 += __shfl_down(p1, off, 64);
        }
        if (lane == 0) {
            const float L2E = 1.4426950408889634f;
            float l0 = p0 + bp[0], l1 = p1 + bp[1];
            float e10 = __builtin_amdgcn_exp2f((l1 - l0) * L2E);
            float e01 = __builtin_amdgcn_exp2f((l0 - l1) * L2E);
            out[B_ * T_ * S_ + row * 2 + 0] = __builtin_amdgcn_rcpf(1.f + e10);
            out[B_ * T_ * S_ + row * 2 + 1] = __builtin_amdgcn_rcpf(1.f + e01);
        }
    }
}

// ---------------------------------------------------------------------------
// Phase-A helper: one wave computes NRG rowgroups x 4 colgroups of lin+exp
// for d-chunk c, writing lx[dloc][row] (row relative to lx base), stride LDSTR.
// ---------------------------------------------------------------------------
template<int NRG, int LDSTR>
__device__ __forceinline__ void do_phaseA(
    const short8 (&af)[2][8], const unsigned short* __restrict__ wtbase,
    const float* __restrict__ bias, float* lx, int c, int n, int quad)
{
    #pragma unroll
    for (int cg = 0; cg < 4; cg++) {
        const int gcol = c * 4 + cg;                 // global colgroup 0..15
        const unsigned short* bptr = &wtbase[(gcol * 16 + n) * D_ + quad * 8];
        short8 bf[8];
        #pragma unroll
        for (int ks = 0; ks < 8; ks++) bf[ks] = *(const short8*)&bptr[ks * 32];
        const int dloc = cg * 16 + n;                // 0..63 within chunk
        const float bv = bias[gcol * 16 + n];
        #pragma unroll
        for (int j = 0; j < NRG; j++) {
            f32x4 a4 = {0.f, 0.f, 0.f, 0.f};
            #pragma unroll
            for (int ks = 0; ks < 8; ks++)
                a4 = __builtin_amdgcn_mfma_f32_16x16x32_bf16(af[j][ks], bf[ks], a4, 0, 0, 0);
            float4 o;
            o.x = __builtin_amdgcn_exp2f((a4[0] + bv) * K2F);
            o.y = __builtin_amdgcn_exp2f((a4[1] + bv) * K2F);
            o.z = __builtin_amdgcn_exp2f((a4[2] + bv) * K2F);
            o.w = __builtin_amdgcn_exp2f((a4[3] + bv) * K2F);
            *(float4*)&lx[dloc * LDSTR + j * 16 + quad * 4] = o;
        }
    }
}

// ---------------------------------------------------------------------------
// K2: mega v3. Tile 64s x 32t, grid (8,16,4) = 512 blocks = 2 blocks/CU
// (8 waves/CU = 2/SIMD for latency hiding). D chunked by 64.
// Phase A: waves 0,1 -> s-mat (2 rowgroups each); waves 2,3 -> t-mat (1 each).
// Phase B: 4s x 2t per thread; W_res read from global (scalar loads).
// genP = C0 - 2 * sum_d w_d / (1 + ys*yt),  C0 = sum w + b_res.
// ---------------------------------------------------------------------------
#define LSTR 68
#define TSTR 36
__global__ __launch_bounds__(256, 2) void mega_kernel(
    const unsigned short* __restrict__ abf, const unsigned short* __restrict__ wtb,
    const float* __restrict__ bsrc, const float* __restrict__ btgt,
    const float* __restrict__ Wres, const float* __restrict__ bres,
    float* __restrict__ out)
{
    __shared__ float ls[64 * LSTR];   // [d][s row], 17.4 KB
    __shared__ float lt[64 * TSTR];   // [d][t row], 9.2 KB
    __shared__ float c0s;

    const int tid = threadIdx.x;
    const int lane = tid & 63, w = tid >> 6;
    const int s0 = blockIdx.x * 64;
    const int t0 = blockIdx.y * 32;
    const int b  = blockIdx.z;

    if (w == 0) {
        float s = Wres[lane] + Wres[lane + 64] + Wres[lane + 128] + Wres[lane + 192];
        #pragma unroll
        for (int off = 32; off > 0; off >>= 1) s += __shfl_xor(s, off, 64);
        if (lane == 0) c0s = s + bres[0];
    }

    // phase-A wave mapping
    const int mat = w >> 1;            // 0 = s-mat (64 rows), 1 = t-mat (32 rows)
    const int h   = w & 1;
    const int n = lane & 15, quad = lane >> 4;
    const int rgbase = mat ? h : 2 * h;
    const int R0 = mat ? (NSRC + b * T_ + t0) : (b * S_ + s0);

    // Resident A-frags (full K): s-waves 2 rowgroups, t-waves 1.
    short8 af[2][8];
    #pragma unroll
    for (int ks = 0; ks < 8; ks++)
        af[0][ks] = *(const short8*)&abf[(R0 + rgbase * 16 + n) * D_ + ks * 32 + quad * 8];
    if (mat == 0) {
        #pragma unroll
        for (int ks = 0; ks < 8; ks++)
            af[1][ks] = *(const short8*)&abf[(R0 + (rgbase + 1) * 16 + n) * D_ + ks * 32 + quad * 8];
    }

    // phase-B thread mapping
    const int m = tid & 15;    // s = s0 + 4m..4m+3
    const int g = tid >> 4;    // t = t0 + 2g..2g+1
    float acc[2][4];
    #pragma unroll
    for (int i = 0; i < 2; i++)
        #pragma unroll
        for (int j = 0; j < 4; j++) acc[i][j] = 0.f;

    for (int c = 0; c < 4; c++) {
        // ---- Phase A ----
        if (mat == 0)
            do_phaseA<2, LSTR>(af, wtb, bsrc, ls + rgbase * 16, c, n, quad);
        else
            do_phaseA<1, TSTR>(af, wtb + 256 * D_, btgt, lt + rgbase * 16, c, n, quad);
        __syncthreads();

        // ---- Phase B: 64 k-steps, 8 rcp + 16 fma each ----
        const float* wp = &Wres[c * 64];
        #pragma unroll 8
        for (int k = 0; k < 64; k++) {
            float4 av = *(const float4*)&ls[k * LSTR + 4 * m];
            float2 cv = *(const float2*)&lt[k * TSTR + 2 * g];
            float wv = wp[k];                        // uniform -> s_load
            float a0 = av.x, a1 = av.y, a2 = av.z, a3 = av.w;
            float c0 = cv.x, c1 = cv.y;
            float r;
            r = __builtin_amdgcn_rcpf(fmaf(c0, a0, 1.f)); acc[0][0] = fmaf(wv, r, acc[0][0]);
            r = __builtin_amdgcn_rcpf(fmaf(c0, a1, 1.f)); acc[0][1] = fmaf(wv, r, acc[0][1]);
            r = __builtin_amdgcn_rcpf(fmaf(c0, a2, 1.f)); acc[0][2] = fmaf(wv, r, acc[0][2]);
            r = __builtin_amdgcn_rcpf(fmaf(c0, a3, 1.f)); acc[0][3] = fmaf(wv, r, acc[0][3]);
            r = __builtin_amdgcn_rcpf(fmaf(c1, a0, 1.f)); acc[1][0] = fmaf(wv, r, acc[1][0]);
            r = __builtin_amdgcn_rcpf(fmaf(c1, a1, 1.f)); acc[1][1] = fmaf(wv, r, acc[1][1]);
            r = __builtin_amdgcn_rcpf(fmaf(c1, a2, 1.f)); acc[1][2] = fmaf(wv, r, acc[1][2]);
            r = __builtin_amdgcn_rcpf(fmaf(c1, a3, 1.f)); acc[1][3] = fmaf(wv, r, acc[1][3]);
        }
        __syncthreads();
    }

    const float C0 = c0s;
    #pragma unroll
    for (int i = 0; i < 2; i++) {
        float4 o;
        o.x = C0 - 2.f * acc[i][0];
        o.y = C0 - 2.f * acc[i][1];
        o.z = C0 - 2.f * acc[i][2];
        o.w = C0 - 2.f * acc[i][3];
        *(float4*)&out[(b * T_ + t0 + 2 * g + i) * S_ + s0 + 4 * m] = o;
    }
}

extern "C" void kernel_launch(void* const* d_in, const int* in_sizes, int n_in,
                              void* d_out, int out_size, void* d_ws, size_t ws_size,
                              hipStream_t stream) {
    const float* source = (const float*)d_in[0];
    const float* target = (const float*)d_in[1];
    const float* W_src  = (const float*)d_in[2];
    const float* b_src  = (const float*)d_in[3];
    const float* W_tgt  = (const float*)d_in[4];
    const float* b_tgt  = (const float*)d_in[5];
    const float* W_res  = (const float*)d_in[6];
    const float* b_res  = (const float*)d_in[7];
    const float* W_prob = (const float*)d_in[8];
    const float* b_prob = (const float*)d_in[9];
    float* out = (float*)d_out;

    unsigned short* abf = (unsigned short*)d_ws;        // 4096*256 bf16 = 2 MB
    unsigned short* wtb = abf + 2 * NSRC * D_;          // 2*256*256 bf16 = 256 KB

    prep_kernel<<<1568, 256, 0, stream>>>(source, target, W_src, W_tgt,
                                          W_prob, b_prob, abf, wtb, out);
    mega_kernel<<<dim3(8, 16, 4), 256, 0, stream>>>(abf, wtb, b_src, b_tgt,
                                                    W_res, b_res, out);
}

// Round 6
// 125.608 us; speedup vs baseline: 1.1102x; 1.1102x over previous
//
#include <hip/hip_runtime.h>

#define B_ 4
#define S_ 512
#define T_ 512
#define D_ 256
#define NSRC (B_ * S_)            // 2048 source rows
#define K2F 2.8853900817779268f   // 2*log2(e): exp2(x*K2F) = e^(2x)

typedef __attribute__((ext_vector_type(8))) short short8;   // 8 bf16
typedef __attribute__((ext_vector_type(4))) float f32x4;

__device__ __forceinline__ unsigned short f2bf(float f) {
    union { float f; unsigned u; } v; v.f = f;
    unsigned r = v.u + 0x7FFF + ((v.u >> 16) & 1);   // RNE
    return (unsigned short)(r >> 16);
}

// ---------------------------------------------------------------------------
// K1: prep (validated R3). blocks 0..1023: cast [src;tgt] -> abf bf16.
//     blocks 1024..1055: W -> WT bf16 via LDS 64x64 tile transpose.
//     blocks 1056..1567: prob = softmax(target @ W_prob + b_prob).
// ---------------------------------------------------------------------------
__global__ __launch_bounds__(256) void prep_kernel(
    const float* __restrict__ src, const float* __restrict__ tgt,
    const float* __restrict__ Wsrc, const float* __restrict__ Wtgt,
    const float* __restrict__ Wp, const float* __restrict__ bp,
    unsigned short* __restrict__ abf, unsigned short* __restrict__ wtb,
    float* __restrict__ out)
{
    __shared__ float tl[64 * 65];
    const int blk = blockIdx.x, tid = threadIdx.x;

    if (blk < 1024) {
        int i4 = blk * 256 + tid;
        const int half = NSRC * D_ / 4;
        const float4* in = (i4 < half) ? (const float4*)src : (const float4*)tgt;
        int j = (i4 < half) ? i4 : i4 - half;
        float4 v = in[j];
        ushort4 o;
        o.x = f2bf(v.x); o.y = f2bf(v.y); o.z = f2bf(v.z); o.w = f2bf(v.w);
        *(ushort4*)&abf[i4 * 4] = o;
    } else if (blk < 1056) {
        int wb = blk - 1024;
        int e = wb >> 4, ti = wb & 15, tr = ti >> 2, tc = ti & 3;
        int r0 = tr * 64, c0 = tc * 64;
        const float* W = e ? Wtgt : Wsrc;
        #pragma unroll
        for (int it = 0; it < 4; it++) {
            int rr = (tid >> 4) + it * 16;
            int cc = (tid & 15) * 4;
            float4 v = *(const float4*)&W[(r0 + rr) * D_ + c0 + cc];
            tl[(cc + 0) * 65 + rr] = v.x;
            tl[(cc + 1) * 65 + rr] = v.y;
            tl[(cc + 2) * 65 + rr] = v.z;
            tl[(cc + 3) * 65 + rr] = v.w;
        }
        __syncthreads();
        #pragma unroll
        for (int it = 0; it < 2; it++) {
            int jj = (tid >> 3) + it * 32;
            int kk = (tid & 7) * 8;
            ushort4 lo, hi;
            lo.x = f2bf(tl[jj * 65 + kk + 0]); lo.y = f2bf(tl[jj * 65 + kk + 1]);
            lo.z = f2bf(tl[jj * 65 + kk + 2]); lo.w = f2bf(tl[jj * 65 + kk + 3]);
            hi.x = f2bf(tl[jj * 65 + kk + 4]); hi.y = f2bf(tl[jj * 65 + kk + 5]);
            hi.z = f2bf(tl[jj * 65 + kk + 6]); hi.w = f2bf(tl[jj * 65 + kk + 7]);
            int idx = (e * 256 + c0 + jj) * D_ + r0 + kk;
            *(ushort4*)&wtb[idx] = lo;
            *(ushort4*)&wtb[idx + 4] = hi;
        }
    } else {
        int row  = (blk - 1056) * 4 + (tid >> 6);
        int lane = tid & 63;
        float p0 = 0.f, p1 = 0.f;
        #pragma unroll
        for (int i = 0; i < 4; i++) {
            int d = lane + i * 64;
            float v = tgt[row * D_ + d];
            float2 w = *(const float2*)&Wp[d * 2];
            p0 = fmaf(v, w.x, p0);
            p1 = fmaf(v, w.y, p1);
        }
        #pragma unroll
        for (int off = 32; off > 0; off >>= 1) {
            p0 += __shfl_down(p0, off, 64);
            p1 += __shfl_down(p1, off, 64);
        }
        if (lane == 0) {
            const float L2E = 1.4426950408889634f;
            float l0 = p0 + bp[0], l1 = p1 + bp[1];
            float e10 = __builtin_amdgcn_exp2f((l1 - l0) * L2E);
            float e01 = __builtin_amdgcn_exp2f((l0 - l1) * L2E);
            out[B_ * T_ * S_ + row * 2 + 0] = __builtin_amdgcn_rcpf(1.f + e10);
            out[B_ * T_ * S_ + row * 2 + 1] = __builtin_amdgcn_rcpf(1.f + e01);
        }
    }
}

// ---------------------------------------------------------------------------
// K2: mega v4. Tile 64s x 64t, grid (8,8,4) = 256 blocks = 1/CU (1 wave/SIMD).
// Software-pipelined: double-buffered LDS d-chunks; per loop iter the wave
// issues phaseA(c+1) (global bf loads + MFMA + exp2 + ds_write into buf^1)
// BEFORE phaseB(c) (the 12K-cycle rcp/fma block on buf), so phase-A latency
// hides under phase-B compute. One barrier per chunk (5 total vs 8 in R4).
// Phase A: wave w: mat=w>>1 (s/t), rowgroups {2*(w&1), 2*(w&1)+1}; af[2][8]
// resident (full K for its 32 rows); 4 colgroups per chunk streamed from wtb.
// Phase B: 4s x 4t per thread, 16 rcp + 32 fma per k; Wres via s_load.
// genP = C0 - 2 * sum_d w_d / (1 + ys*yt),  C0 = sum w + b_res.
// ---------------------------------------------------------------------------
#define LSTR 68
__global__ __launch_bounds__(256, 1) void mega_kernel(
    const unsigned short* __restrict__ abf, const unsigned short* __restrict__ wtb,
    const float* __restrict__ bsrc, const float* __restrict__ btgt,
    const float* __restrict__ Wres, const float* __restrict__ bres,
    float* __restrict__ out)
{
    __shared__ float ls[2][64 * LSTR];   // [buf][d][s], 2 x 17.4 KB
    __shared__ float lt[2][64 * LSTR];   // [buf][d][t], 2 x 17.4 KB
    __shared__ float c0s;

    const int tid = threadIdx.x;
    const int lane = tid & 63, w = tid >> 6;
    const int s0 = blockIdx.x * 64;
    const int t0 = blockIdx.y * 64;
    const int b  = blockIdx.z;

    if (w == 0) {
        float s = Wres[lane] + Wres[lane + 64] + Wres[lane + 128] + Wres[lane + 192];
        #pragma unroll
        for (int off = 32; off > 0; off >>= 1) s += __shfl_xor(s, off, 64);
        if (lane == 0) c0s = s + bres[0];
    }

    // phase-A wave mapping: mat = w>>1, rowgroups rb, rb+1 where rb = 2*(w&1)
    const int mat = w >> 1;
    const int rb  = 2 * (w & 1);
    const int n = lane & 15, quad = lane >> 4;
    const float* bias = mat ? btgt : bsrc;
    const unsigned short* wtbase = wtb + mat * 256 * D_;
    const int R0 = mat ? (NSRC + b * T_ + t0) : (b * S_ + s0);

    // Resident A-frags: 2 rowgroups x full K (64 VGPR)
    short8 af[2][8];
    #pragma unroll
    for (int rg = 0; rg < 2; rg++)
        #pragma unroll
        for (int ks = 0; ks < 8; ks++)
            af[rg][ks] = *(const short8*)&abf[(R0 + (rb + rg) * 16 + n) * D_ + ks * 32 + quad * 8];

    // phase-B thread mapping
    const int m = tid & 15;    // s = s0 + 4m..4m+3
    const int g = tid >> 4;    // t = t0 + 4g..4g+3
    float acc[4][4];
    #pragma unroll
    for (int i = 0; i < 4; i++)
        #pragma unroll
        for (int j = 0; j < 4; j++) acc[i][j] = 0.f;

    // ---- phase A for a chunk c into buffer bi ----
    auto phaseA = [&](int c, int bi) {
        float* lx = (mat ? lt[bi] : ls[bi]);
        #pragma unroll
        for (int cg = 0; cg < 4; cg++) {
            const int gcol = c * 4 + cg;
            const unsigned short* bptr = &wtbase[(gcol * 16 + n) * D_ + quad * 8];
            short8 bf[8];
            #pragma unroll
            for (int ks = 0; ks < 8; ks++) bf[ks] = *(const short8*)&bptr[ks * 32];
            const int dloc = cg * 16 + n;
            const float bv = bias[gcol * 16 + n];
            #pragma unroll
            for (int rg = 0; rg < 2; rg++) {
                f32x4 a4 = {0.f, 0.f, 0.f, 0.f};
                #pragma unroll
                for (int ks = 0; ks < 8; ks++)
                    a4 = __builtin_amdgcn_mfma_f32_16x16x32_bf16(af[rg][ks], bf[ks], a4, 0, 0, 0);
                float4 o;
                o.x = __builtin_amdgcn_exp2f((a4[0] + bv) * K2F);
                o.y = __builtin_amdgcn_exp2f((a4[1] + bv) * K2F);
                o.z = __builtin_amdgcn_exp2f((a4[2] + bv) * K2F);
                o.w = __builtin_amdgcn_exp2f((a4[3] + bv) * K2F);
                *(float4*)&lx[dloc * LSTR + (rb + rg) * 16 + quad * 4] = o;
            }
        }
    };

    phaseA(0, 0);
    __syncthreads();

    for (int c = 0; c < 4; c++) {
        const int bi = c & 1;
        if (c < 3) phaseA(c + 1, bi ^ 1);   // overlaps with phaseB(c) below

        const float* lsb = ls[bi];
        const float* ltb = lt[bi];
        const float* wp = &Wres[c * 64];
        #pragma unroll 8
        for (int k = 0; k < 64; k++) {
            float4 av = *(const float4*)&lsb[k * LSTR + 4 * m];
            float4 cv = *(const float4*)&ltb[k * LSTR + 4 * g];
            float wv = wp[k];                        // uniform -> s_load
            float a0 = av.x, a1 = av.y, a2 = av.z, a3 = av.w;
            float c0 = cv.x, c1 = cv.y, c2 = cv.z, c3 = cv.w;
            float r;
            r = __builtin_amdgcn_rcpf(fmaf(c0, a0, 1.f)); acc[0][0] = fmaf(wv, r, acc[0][0]);
            r = __builtin_amdgcn_rcpf(fmaf(c0, a1, 1.f)); acc[0][1] = fmaf(wv, r, acc[0][1]);
            r = __builtin_amdgcn_rcpf(fmaf(c0, a2, 1.f)); acc[0][2] = fmaf(wv, r, acc[0][2]);
            r = __builtin_amdgcn_rcpf(fmaf(c0, a3, 1.f)); acc[0][3] = fmaf(wv, r, acc[0][3]);
            r = __builtin_amdgcn_rcpf(fmaf(c1, a0, 1.f)); acc[1][0] = fmaf(wv, r, acc[1][0]);
            r = __builtin_amdgcn_rcpf(fmaf(c1, a1, 1.f)); acc[1][1] = fmaf(wv, r, acc[1][1]);
            r = __builtin_amdgcn_rcpf(fmaf(c1, a2, 1.f)); acc[1][2] = fmaf(wv, r, acc[1][2]);
            r = __builtin_amdgcn_rcpf(fmaf(c1, a3, 1.f)); acc[1][3] = fmaf(wv, r, acc[1][3]);
            r = __builtin_amdgcn_rcpf(fmaf(c2, a0, 1.f)); acc[2][0] = fmaf(wv, r, acc[2][0]);
            r = __builtin_amdgcn_rcpf(fmaf(c2, a1, 1.f)); acc[2][1] = fmaf(wv, r, acc[2][1]);
            r = __builtin_amdgcn_rcpf(fmaf(c2, a2, 1.f)); acc[2][2] = fmaf(wv, r, acc[2][2]);
            r = __builtin_amdgcn_rcpf(fmaf(c2, a3, 1.f)); acc[2][3] = fmaf(wv, r, acc[2][3]);
            r = __builtin_amdgcn_rcpf(fmaf(c3, a0, 1.f)); acc[3][0] = fmaf(wv, r, acc[3][0]);
            r = __builtin_amdgcn_rcpf(fmaf(c3, a1, 1.f)); acc[3][1] = fmaf(wv, r, acc[3][1]);
            r = __builtin_amdgcn_rcpf(fmaf(c3, a2, 1.f)); acc[3][2] = fmaf(wv, r, acc[3][2]);
            r = __builtin_amdgcn_rcpf(fmaf(c3, a3, 1.f)); acc[3][3] = fmaf(wv, r, acc[3][3]);
        }
        __syncthreads();
    }

    const float C0 = c0s;
    #pragma unroll
    for (int i = 0; i < 4; i++) {
        float4 o;
        o.x = C0 - 2.f * acc[i][0];
        o.y = C0 - 2.f * acc[i][1];
        o.z = C0 - 2.f * acc[i][2];
        o.w = C0 - 2.f * acc[i][3];
        *(float4*)&out[(b * T_ + t0 + 4 * g + i) * S_ + s0 + 4 * m] = o;
    }
}

extern "C" void kernel_launch(void* const* d_in, const int* in_sizes, int n_in,
                              void* d_out, int out_size, void* d_ws, size_t ws_size,
                              hipStream_t stream) {
    const float* source = (const float*)d_in[0];
    const float* target = (const float*)d_in[1];
    const float* W_src  = (const float*)d_in[2];
    const float* b_src  = (const float*)d_in[3];
    const float* W_tgt  = (const float*)d_in[4];
    const float* b_tgt  = (const float*)d_in[5];
    const float* W_res  = (const float*)d_in[6];
    const float* b_res  = (const float*)d_in[7];
    const float* W_prob = (const float*)d_in[8];
    const float* b_prob = (const float*)d_in[9];
    float* out = (float*)d_out;

    unsigned short* abf = (unsigned short*)d_ws;        // 4096*256 bf16 = 2 MB
    unsigned short* wtb = abf + 2 * NSRC * D_;          // 2*256*256 bf16 = 256 KB

    prep_kernel<<<1568, 256, 0, stream>>>(source, target, W_src, W_tgt,
                                          W_prob, b_prob, abf, wtb, out);
    mega_kernel<<<dim3(8, 8, 4), 256, 0, stream>>>(abf, wtb, b_src, b_tgt,
                                                   W_res, b_res, out);
}

// Round 7
// 122.361 us; speedup vs baseline: 1.1396x; 1.0265x over previous
//
#include <hip/hip_runtime.h>

#define B_ 4
#define S_ 512
#define T_ 512
#define D_ 256
#define NSRC (B_ * S_)            // 2048 source rows
#define K2F 2.8853900817779268f   // 2*log2(e): exp2(x*K2F) = e^(2x)

typedef __attribute__((ext_vector_type(8))) short short8;   // 8 bf16
typedef __attribute__((ext_vector_type(4))) float f32x4;

__device__ __forceinline__ unsigned short f2bf(float f) {
    union { float f; unsigned u; } v; v.f = f;
    unsigned r = v.u + 0x7FFF + ((v.u >> 16) & 1);   // RNE
    return (unsigned short)(r >> 16);
}

// ---------------------------------------------------------------------------
// K1: prep (validated R3). blocks 0..1023: cast [src;tgt] -> abf bf16.
//     blocks 1024..1055: W -> WT bf16 via LDS 64x64 tile transpose.
//     blocks 1056..1567: prob = softmax(target @ W_prob + b_prob).
// ---------------------------------------------------------------------------
__global__ __launch_bounds__(256) void prep_kernel(
    const float* __restrict__ src, const float* __restrict__ tgt,
    const float* __restrict__ Wsrc, const float* __restrict__ Wtgt,
    const float* __restrict__ Wp, const float* __restrict__ bp,
    unsigned short* __restrict__ abf, unsigned short* __restrict__ wtb,
    float* __restrict__ out)
{
    __shared__ float tl[64 * 65];
    const int blk = blockIdx.x, tid = threadIdx.x;

    if (blk < 1024) {
        int i4 = blk * 256 + tid;
        const int half = NSRC * D_ / 4;
        const float4* in = (i4 < half) ? (const float4*)src : (const float4*)tgt;
        int j = (i4 < half) ? i4 : i4 - half;
        float4 v = in[j];
        ushort4 o;
        o.x = f2bf(v.x); o.y = f2bf(v.y); o.z = f2bf(v.z); o.w = f2bf(v.w);
        *(ushort4*)&abf[i4 * 4] = o;
    } else if (blk < 1056) {
        int wb = blk - 1024;
        int e = wb >> 4, ti = wb & 15, tr = ti >> 2, tc = ti & 3;
        int r0 = tr * 64, c0 = tc * 64;
        const float* W = e ? Wtgt : Wsrc;
        #pragma unroll
        for (int it = 0; it < 4; it++) {
            int rr = (tid >> 4) + it * 16;
            int cc = (tid & 15) * 4;
            float4 v = *(const float4*)&W[(r0 + rr) * D_ + c0 + cc];
            tl[(cc + 0) * 65 + rr] = v.x;
            tl[(cc + 1) * 65 + rr] = v.y;
            tl[(cc + 2) * 65 + rr] = v.z;
            tl[(cc + 3) * 65 + rr] = v.w;
        }
        __syncthreads();
        #pragma unroll
        for (int it = 0; it < 2; it++) {
            int jj = (tid >> 3) + it * 32;
            int kk = (tid & 7) * 8;
            ushort4 lo, hi;
            lo.x = f2bf(tl[jj * 65 + kk + 0]); lo.y = f2bf(tl[jj * 65 + kk + 1]);
            lo.z = f2bf(tl[jj * 65 + kk + 2]); lo.w = f2bf(tl[jj * 65 + kk + 3]);
            hi.x = f2bf(tl[jj * 65 + kk + 4]); hi.y = f2bf(tl[jj * 65 + kk + 5]);
            hi.z = f2bf(tl[jj * 65 + kk + 6]); hi.w = f2bf(tl[jj * 65 + kk + 7]);
            int idx = (e * 256 + c0 + jj) * D_ + r0 + kk;
            *(ushort4*)&wtb[idx] = lo;
            *(ushort4*)&wtb[idx + 4] = hi;
        }
    } else {
        int row  = (blk - 1056) * 4 + (tid >> 6);
        int lane = tid & 63;
        float p0 = 0.f, p1 = 0.f;
        #pragma unroll
        for (int i = 0; i < 4; i++) {
            int d = lane + i * 64;
            float v = tgt[row * D_ + d];
            float2 w = *(const float2*)&Wp[d * 2];
            p0 = fmaf(v, w.x, p0);
            p1 = fmaf(v, w.y, p1);
        }
        #pragma unroll
        for (int off = 32; off > 0; off >>= 1) {
            p0 += __shfl_down(p0, off, 64);
            p1 += __shfl_down(p1, off, 64);
        }
        if (lane == 0) {
            const float L2E = 1.4426950408889634f;
            float l0 = p0 + bp[0], l1 = p1 + bp[1];
            float e10 = __builtin_amdgcn_exp2f((l1 - l0) * L2E);
            float e01 = __builtin_amdgcn_exp2f((l0 - l1) * L2E);
            out[B_ * T_ * S_ + row * 2 + 0] = __builtin_amdgcn_rcpf(1.f + e10);
            out[B_ * T_ * S_ + row * 2 + 1] = __builtin_amdgcn_rcpf(1.f + e01);
        }
    }
}

// ---------------------------------------------------------------------------
// K2: mega v5 — producer/consumer wave specialization.
// 512 threads = 8 waves, grid (8,8,4) = 256 blocks = 1 block/CU = 2 waves/SIMD
// (1 producer + 1 consumer per SIMD; cross-wave latency hiding).
// Producers (waves 0-3): phase A for d-chunk c+1 into double-buffered LDS:
//   wave pw: mat=pw>>1, rowgroups 2*(pw&1)+{0,1}; af[2][8] resident (full K);
//   4 colgroups/chunk streamed from wtb; MFMA -> exp2 -> ds_write b128.
// Consumers (waves 4-7): phase B on chunk c: 4s x 4t per thread,
//   16 rcp + 32 fma per k; all operands from LDS (wl preloaded; no smem in loop).
// genP = C0 - 2 * sum_d w_d / (1 + ys*yt),  C0 = sum w + b_res.
// ---------------------------------------------------------------------------
#define LSTR 68
__global__ __launch_bounds__(512, 1) void mega_kernel(
    const unsigned short* __restrict__ abf, const unsigned short* __restrict__ wtb,
    const float* __restrict__ bsrc, const float* __restrict__ btgt,
    const float* __restrict__ Wres, const float* __restrict__ bres,
    float* __restrict__ out)
{
    __shared__ float ls[2][64 * LSTR];   // [buf][d][s], 2 x 17.4 KB
    __shared__ float lt[2][64 * LSTR];   // [buf][d][t], 2 x 17.4 KB
    __shared__ float wl[D_];
    __shared__ float c0s;

    const int tid = threadIdx.x;
    const int lane = tid & 63, w = tid >> 6;
    const int s0 = blockIdx.x * 64;
    const int t0 = blockIdx.y * 64;
    const int b  = blockIdx.z;

    if (tid < D_) wl[tid] = Wres[tid];
    if (w == 0) {
        float s = Wres[lane] + Wres[lane + 64] + Wres[lane + 128] + Wres[lane + 192];
        #pragma unroll
        for (int off = 32; off > 0; off >>= 1) s += __shfl_xor(s, off, 64);
        if (lane == 0) c0s = s + bres[0];
    }

    const bool producer = (w < 4);

    // ---- producer state ----
    const int pw  = w & 3;
    const int mat = pw >> 1;             // 0 = s-mat, 1 = t-mat
    const int rb  = 2 * (pw & 1);        // rowgroup base (2 rowgroups = 32 rows)
    const int n = lane & 15, quad = lane >> 4;
    const float* bias = mat ? btgt : bsrc;
    const unsigned short* wtbase = wtb + mat * 256 * D_;
    const int R0 = mat ? (NSRC + b * T_ + t0) : (b * S_ + s0);

    short8 af[2][8];
    if (producer) {
        #pragma unroll
        for (int rg = 0; rg < 2; rg++)
            #pragma unroll
            for (int ks = 0; ks < 8; ks++)
                af[rg][ks] = *(const short8*)&abf[(R0 + (rb + rg) * 16 + n) * D_ + ks * 32 + quad * 8];
    }

    auto phaseA = [&](int c, int bi) {
        float* lx = (mat ? lt[bi] : ls[bi]);
        #pragma unroll
        for (int cg = 0; cg < 4; cg++) {
            const int gcol = c * 4 + cg;
            const unsigned short* bptr = &wtbase[(gcol * 16 + n) * D_ + quad * 8];
            short8 bf[8];
            #pragma unroll
            for (int ks = 0; ks < 8; ks++) bf[ks] = *(const short8*)&bptr[ks * 32];
            const int dloc = cg * 16 + n;
            const float bv = bias[gcol * 16 + n];
            #pragma unroll
            for (int rg = 0; rg < 2; rg++) {
                f32x4 a4 = {0.f, 0.f, 0.f, 0.f};
                #pragma unroll
                for (int ks = 0; ks < 8; ks++)
                    a4 = __builtin_amdgcn_mfma_f32_16x16x32_bf16(af[rg][ks], bf[ks], a4, 0, 0, 0);
                float4 o;
                o.x = __builtin_amdgcn_exp2f((a4[0] + bv) * K2F);
                o.y = __builtin_amdgcn_exp2f((a4[1] + bv) * K2F);
                o.z = __builtin_amdgcn_exp2f((a4[2] + bv) * K2F);
                o.w = __builtin_amdgcn_exp2f((a4[3] + bv) * K2F);
                *(float4*)&lx[dloc * LSTR + (rb + rg) * 16 + quad * 4] = o;
            }
        }
    };

    // ---- consumer state ----
    const int cl = tid - 256;            // 0..255 for consumers
    const int m = cl & 15;               // s = s0 + 4m..4m+3
    const int g = (cl >> 4) & 15;        // t = t0 + 4g..4g+3
    float acc[4][4];
    #pragma unroll
    for (int i = 0; i < 4; i++)
        #pragma unroll
        for (int j = 0; j < 4; j++) acc[i][j] = 0.f;

    if (producer) phaseA(0, 0);
    __syncthreads();

    for (int c = 0; c < 4; c++) {
        const int bi = c & 1;
        if (producer) {
            if (c < 3) phaseA(c + 1, bi ^ 1);
        } else {
            const float* lsb = ls[bi];
            const float* ltb = lt[bi];
            const float* wp = &wl[c * 64];
            #pragma unroll 8
            for (int k = 0; k < 64; k++) {
                float4 av = *(const float4*)&lsb[k * LSTR + 4 * m];
                float4 cv = *(const float4*)&ltb[k * LSTR + 4 * g];
                float wv = wp[k];                    // LDS same-address broadcast
                float a0 = av.x, a1 = av.y, a2 = av.z, a3 = av.w;
                float c0 = cv.x, c1 = cv.y, c2 = cv.z, c3 = cv.w;
                float r;
                r = __builtin_amdgcn_rcpf(fmaf(c0, a0, 1.f)); acc[0][0] = fmaf(wv, r, acc[0][0]);
                r = __builtin_amdgcn_rcpf(fmaf(c0, a1, 1.f)); acc[0][1] = fmaf(wv, r, acc[0][1]);
                r = __builtin_amdgcn_rcpf(fmaf(c0, a2, 1.f)); acc[0][2] = fmaf(wv, r, acc[0][2]);
                r = __builtin_amdgcn_rcpf(fmaf(c0, a3, 1.f)); acc[0][3] = fmaf(wv, r, acc[0][3]);
                r = __builtin_amdgcn_rcpf(fmaf(c1, a0, 1.f)); acc[1][0] = fmaf(wv, r, acc[1][0]);
                r = __builtin_amdgcn_rcpf(fmaf(c1, a1, 1.f)); acc[1][1] = fmaf(wv, r, acc[1][1]);
                r = __builtin_amdgcn_rcpf(fmaf(c1, a2, 1.f)); acc[1][2] = fmaf(wv, r, acc[1][2]);
                r = __builtin_amdgcn_rcpf(fmaf(c1, a3, 1.f)); acc[1][3] = fmaf(wv, r, acc[1][3]);
                r = __builtin_amdgcn_rcpf(fmaf(c2, a0, 1.f)); acc[2][0] = fmaf(wv, r, acc[2][0]);
                r = __builtin_amdgcn_rcpf(fmaf(c2, a1, 1.f)); acc[2][1] = fmaf(wv, r, acc[2][1]);
                r = __builtin_amdgcn_rcpf(fmaf(c2, a2, 1.f)); acc[2][2] = fmaf(wv, r, acc[2][2]);
                r = __builtin_amdgcn_rcpf(fmaf(c2, a3, 1.f)); acc[2][3] = fmaf(wv, r, acc[2][3]);
                r = __builtin_amdgcn_rcpf(fmaf(c3, a0, 1.f)); acc[3][0] = fmaf(wv, r, acc[3][0]);
                r = __builtin_amdgcn_rcpf(fmaf(c3, a1, 1.f)); acc[3][1] = fmaf(wv, r, acc[3][1]);
                r = __builtin_amdgcn_rcpf(fmaf(c3, a2, 1.f)); acc[3][2] = fmaf(wv, r, acc[3][2]);
                r = __builtin_amdgcn_rcpf(fmaf(c3, a3, 1.f)); acc[3][3] = fmaf(wv, r, acc[3][3]);
            }
        }
        __syncthreads();
    }

    if (!producer) {
        const float C0 = c0s;
        #pragma unroll
        for (int i = 0; i < 4; i++) {
            float4 o;
            o.x = C0 - 2.f * acc[i][0];
            o.y = C0 - 2.f * acc[i][1];
            o.z = C0 - 2.f * acc[i][2];
            o.w = C0 - 2.f * acc[i][3];
            *(float4*)&out[(b * T_ + t0 + 4 * g + i) * S_ + s0 + 4 * m] = o;
        }
    }
}

extern "C" void kernel_launch(void* const* d_in, const int* in_sizes, int n_in,
                              void* d_out, int out_size, void* d_ws, size_t ws_size,
                              hipStream_t stream) {
    const float* source = (const float*)d_in[0];
    const float* target = (const float*)d_in[1];
    const float* W_src  = (const float*)d_in[2];
    const float* b_src  = (const float*)d_in[3];
    const float* W_tgt  = (const float*)d_in[4];
    const float* b_tgt  = (const float*)d_in[5];
    const float* W_res  = (const float*)d_in[6];
    const float* b_res  = (const float*)d_in[7];
    const float* W_prob = (const float*)d_in[8];
    const float* b_prob = (const float*)d_in[9];
    float* out = (float*)d_out;

    unsigned short* abf = (unsigned short*)d_ws;        // 4096*256 bf16 = 2 MB
    unsigned short* wtb = abf + 2 * NSRC * D_;          // 2*256*256 bf16 = 256 KB

    prep_kernel<<<1568, 256, 0, stream>>>(source, target, W_src, W_tgt,
                                          W_prob, b_prob, abf, wtb, out);
    mega_kernel<<<dim3(8, 8, 4), 512, 0, stream>>>(abf, wtb, b_src, b_tgt,
                                                   W_res, b_res, out);
}

// Round 8
// 114.737 us; speedup vs baseline: 1.2154x; 1.0665x over previous
//
#include <hip/hip_runtime.h>

#define B_ 4
#define S_ 512
#define T_ 512
#define D_ 256
#define NSRC (B_ * S_)            // 2048 source rows
#define K2F 2.8853900817779268f   // 2*log2(e): exp2(x*K2F) = e^(2x)

typedef __attribute__((ext_vector_type(8))) short short8;   // 8 bf16
typedef __attribute__((ext_vector_type(4))) float f32x4;
typedef __attribute__((ext_vector_type(2))) float f32x2;

__device__ __forceinline__ unsigned short f2bf(float f) {
    union { float f; unsigned u; } v; v.f = f;
    unsigned r = v.u + 0x7FFF + ((v.u >> 16) & 1);   // RNE
    return (unsigned short)(r >> 16);
}

// ---------------------------------------------------------------------------
// K1: prep (validated R3). blocks 0..1023: cast [src;tgt] -> abf bf16.
//     blocks 1024..1055: W -> WT bf16 via LDS 64x64 tile transpose.
//     blocks 1056..1567: prob = softmax(target @ W_prob + b_prob).
// ---------------------------------------------------------------------------
__global__ __launch_bounds__(256) void prep_kernel(
    const float* __restrict__ src, const float* __restrict__ tgt,
    const float* __restrict__ Wsrc, const float* __restrict__ Wtgt,
    const float* __restrict__ Wp, const float* __restrict__ bp,
    unsigned short* __restrict__ abf, unsigned short* __restrict__ wtb,
    float* __restrict__ out)
{
    __shared__ float tl[64 * 65];
    const int blk = blockIdx.x, tid = threadIdx.x;

    if (blk < 1024) {
        int i4 = blk * 256 + tid;
        const int half = NSRC * D_ / 4;
        const float4* in = (i4 < half) ? (const float4*)src : (const float4*)tgt;
        int j = (i4 < half) ? i4 : i4 - half;
        float4 v = in[j];
        ushort4 o;
        o.x = f2bf(v.x); o.y = f2bf(v.y); o.z = f2bf(v.z); o.w = f2bf(v.w);
        *(ushort4*)&abf[i4 * 4] = o;
    } else if (blk < 1056) {
        int wb = blk - 1024;
        int e = wb >> 4, ti = wb & 15, tr = ti >> 2, tc = ti & 3;
        int r0 = tr * 64, c0 = tc * 64;
        const float* W = e ? Wtgt : Wsrc;
        #pragma unroll
        for (int it = 0; it < 4; it++) {
            int rr = (tid >> 4) + it * 16;
            int cc = (tid & 15) * 4;
            float4 v = *(const float4*)&W[(r0 + rr) * D_ + c0 + cc];
            tl[(cc + 0) * 65 + rr] = v.x;
            tl[(cc + 1) * 65 + rr] = v.y;
            tl[(cc + 2) * 65 + rr] = v.z;
            tl[(cc + 3) * 65 + rr] = v.w;
        }
        __syncthreads();
        #pragma unroll
        for (int it = 0; it < 2; it++) {
            int jj = (tid >> 3) + it * 32;
            int kk = (tid & 7) * 8;
            ushort4 lo, hi;
            lo.x = f2bf(tl[jj * 65 + kk + 0]); lo.y = f2bf(tl[jj * 65 + kk + 1]);
            lo.z = f2bf(tl[jj * 65 + kk + 2]); lo.w = f2bf(tl[jj * 65 + kk + 3]);
            hi.x = f2bf(tl[jj * 65 + kk + 4]); hi.y = f2bf(tl[jj * 65 + kk + 5]);
            hi.z = f2bf(tl[jj * 65 + kk + 6]); hi.w = f2bf(tl[jj * 65 + kk + 7]);
            int idx = (e * 256 + c0 + jj) * D_ + r0 + kk;
            *(ushort4*)&wtb[idx] = lo;
            *(ushort4*)&wtb[idx + 4] = hi;
        }
    } else {
        int row  = (blk - 1056) * 4 + (tid >> 6);
        int lane = tid & 63;
        float p0 = 0.f, p1 = 0.f;
        #pragma unroll
        for (int i = 0; i < 4; i++) {
            int d = lane + i * 64;
            float v = tgt[row * D_ + d];
            float2 w = *(const float2*)&Wp[d * 2];
            p0 = fmaf(v, w.x, p0);
            p1 = fmaf(v, w.y, p1);
        }
        #pragma unroll
        for (int off = 32; off > 0; off >>= 1) {
            p0 += __shfl_down(p0, off, 64);
            p1 += __shfl_down(p1, off, 64);
        }
        if (lane == 0) {
            const float L2E = 1.4426950408889634f;
            float l0 = p0 + bp[0], l1 = p1 + bp[1];
            float e10 = __builtin_amdgcn_exp2f((l1 - l0) * L2E);
            float e01 = __builtin_amdgcn_exp2f((l0 - l1) * L2E);
            out[B_ * T_ * S_ + row * 2 + 0] = __builtin_amdgcn_rcpf(1.f + e10);
            out[B_ * T_ * S_ + row * 2 + 1] = __builtin_amdgcn_rcpf(1.f + e01);
        }
    }
}

// ---------------------------------------------------------------------------
// K2: mega v6 — producer/consumer waves + consumer register prefetch.
// 512 threads = 8 waves, grid (8,8,4) = 256 blocks = 1/CU = 2 waves/SIMD.
// Producers (waves 0-3): phase A (MFMA lin + exp2) into double-buffered LDS.
// Consumers (waves 4-7): phase B with k+1 LDS prefetch into registers so the
//   ~192-cy compute block per k hides ds_read latency; Wres via scalar loads;
//   accumulators as f32x2 to encourage v_pk_fma_f32.
// genP = C0 - 2 * sum_d w_d / (1 + ys*yt),  C0 = sum w + b_res.
// ---------------------------------------------------------------------------
#define LSTR 68
__global__ __launch_bounds__(512, 1) void mega_kernel(
    const unsigned short* __restrict__ abf, const unsigned short* __restrict__ wtb,
    const float* __restrict__ bsrc, const float* __restrict__ btgt,
    const float* __restrict__ Wres, const float* __restrict__ bres,
    float* __restrict__ out)
{
    __shared__ float ls[2][64 * LSTR];   // [buf][d][s]
    __shared__ float lt[2][64 * LSTR];   // [buf][d][t]
    __shared__ float c0s;

    const int tid = threadIdx.x;
    const int lane = tid & 63, w = tid >> 6;
    const int s0 = blockIdx.x * 64;
    const int t0 = blockIdx.y * 64;
    const int b  = blockIdx.z;

    if (w == 0) {
        float s = Wres[lane] + Wres[lane + 64] + Wres[lane + 128] + Wres[lane + 192];
        #pragma unroll
        for (int off = 32; off > 0; off >>= 1) s += __shfl_xor(s, off, 64);
        if (lane == 0) c0s = s + bres[0];
    }

    const bool producer = (w < 4);

    // ---- producer state ----
    const int pw  = w & 3;
    const int mat = pw >> 1;             // 0 = s-mat, 1 = t-mat
    const int rb  = 2 * (pw & 1);        // rowgroup base
    const int n = lane & 15, quad = lane >> 4;
    const float* bias = mat ? btgt : bsrc;
    const unsigned short* wtbase = wtb + mat * 256 * D_;
    const int R0 = mat ? (NSRC + b * T_ + t0) : (b * S_ + s0);

    short8 af[2][8];
    if (producer) {
        #pragma unroll
        for (int rg = 0; rg < 2; rg++)
            #pragma unroll
            for (int ks = 0; ks < 8; ks++)
                af[rg][ks] = *(const short8*)&abf[(R0 + (rb + rg) * 16 + n) * D_ + ks * 32 + quad * 8];
    }

    auto phaseA = [&](int c, int bi) {
        float* lx = (mat ? lt[bi] : ls[bi]);
        #pragma unroll
        for (int cg = 0; cg < 4; cg++) {
            const int gcol = c * 4 + cg;
            const unsigned short* bptr = &wtbase[(gcol * 16 + n) * D_ + quad * 8];
            short8 bf[8];
            #pragma unroll
            for (int ks = 0; ks < 8; ks++) bf[ks] = *(const short8*)&bptr[ks * 32];
            const int dloc = cg * 16 + n;
            const float bv = bias[gcol * 16 + n];
            #pragma unroll
            for (int rg = 0; rg < 2; rg++) {
                f32x4 a4 = {0.f, 0.f, 0.f, 0.f};
                #pragma unroll
                for (int ks = 0; ks < 8; ks++)
                    a4 = __builtin_amdgcn_mfma_f32_16x16x32_bf16(af[rg][ks], bf[ks], a4, 0, 0, 0);
                float4 o;
                o.x = __builtin_amdgcn_exp2f((a4[0] + bv) * K2F);
                o.y = __builtin_amdgcn_exp2f((a4[1] + bv) * K2F);
                o.z = __builtin_amdgcn_exp2f((a4[2] + bv) * K2F);
                o.w = __builtin_amdgcn_exp2f((a4[3] + bv) * K2F);
                *(float4*)&lx[dloc * LSTR + (rb + rg) * 16 + quad * 4] = o;
            }
        }
    };

    // ---- consumer state ----
    const int cl = tid - 256;
    const int m = cl & 15;               // s = s0 + 4m..4m+3
    const int g = (cl >> 4) & 15;        // t = t0 + 4g..4g+3
    f32x2 acc[4][2];
    #pragma unroll
    for (int i = 0; i < 4; i++) {
        acc[i][0] = (f32x2){0.f, 0.f};
        acc[i][1] = (f32x2){0.f, 0.f};
    }

    if (producer) phaseA(0, 0);
    __syncthreads();

    for (int c = 0; c < 4; c++) {
        const int bi = c & 1;
        if (producer) {
            if (c < 3) phaseA(c + 1, bi ^ 1);
        } else {
            const float* lsb = ls[bi];
            const float* ltb = lt[bi];
            const float* wp = &Wres[c * 64];
            float4 av = *(const float4*)&lsb[4 * m];
            float4 cv = *(const float4*)&ltb[4 * g];
            #pragma unroll 8
            for (int k = 0; k < 64; k++) {
                float4 avn = av, cvn = cv;
                if (k < 63) {
                    avn = *(const float4*)&lsb[(k + 1) * LSTR + 4 * m];
                    cvn = *(const float4*)&ltb[(k + 1) * LSTR + 4 * g];
                }
                const float wv = wp[k];              // uniform -> s_load
                const f32x2 w2 = {wv, wv};
                float a0 = av.x, a1 = av.y, a2 = av.z, a3 = av.w;
                float c0 = cv.x, c1 = cv.y, c2 = cv.z, c3 = cv.w;
                f32x2 r;
                r.x = __builtin_amdgcn_rcpf(fmaf(c0, a0, 1.f));
                r.y = __builtin_amdgcn_rcpf(fmaf(c0, a1, 1.f));
                acc[0][0] = r * w2 + acc[0][0];
                r.x = __builtin_amdgcn_rcpf(fmaf(c0, a2, 1.f));
                r.y = __builtin_amdgcn_rcpf(fmaf(c0, a3, 1.f));
                acc[0][1] = r * w2 + acc[0][1];
                r.x = __builtin_amdgcn_rcpf(fmaf(c1, a0, 1.f));
                r.y = __builtin_amdgcn_rcpf(fmaf(c1, a1, 1.f));
                acc[1][0] = r * w2 + acc[1][0];
                r.x = __builtin_amdgcn_rcpf(fmaf(c1, a2, 1.f));
                r.y = __builtin_amdgcn_rcpf(fmaf(c1, a3, 1.f));
                acc[1][1] = r * w2 + acc[1][1];
                r.x = __builtin_amdgcn_rcpf(fmaf(c2, a0, 1.f));
                r.y = __builtin_amdgcn_rcpf(fmaf(c2, a1, 1.f));
                acc[2][0] = r * w2 + acc[2][0];
                r.x = __builtin_amdgcn_rcpf(fmaf(c2, a2, 1.f));
                r.y = __builtin_amdgcn_rcpf(fmaf(c2, a3, 1.f));
                acc[2][1] = r * w2 + acc[2][1];
                r.x = __builtin_amdgcn_rcpf(fmaf(c3, a0, 1.f));
                r.y = __builtin_amdgcn_rcpf(fmaf(c3, a1, 1.f));
                acc[3][0] = r * w2 + acc[3][0];
                r.x = __builtin_amdgcn_rcpf(fmaf(c3, a2, 1.f));
                r.y = __builtin_amdgcn_rcpf(fmaf(c3, a3, 1.f));
                acc[3][1] = r * w2 + acc[3][1];
                av = avn; cv = cvn;
            }
        }
        __syncthreads();
    }

    if (!producer) {
        const float C0 = c0s;
        #pragma unroll
        for (int i = 0; i < 4; i++) {
            float4 o;
            o.x = C0 - 2.f * acc[i][0].x;
            o.y = C0 - 2.f * acc[i][0].y;
            o.z = C0 - 2.f * acc[i][1].x;
            o.w = C0 - 2.f * acc[i][1].y;
            *(float4*)&out[(b * T_ + t0 + 4 * g + i) * S_ + s0 + 4 * m] = o;
        }
    }
}

extern "C" void kernel_launch(void* const* d_in, const int* in_sizes, int n_in,
                              void* d_out, int out_size, void* d_ws, size_t ws_size,
                              hipStream_t stream) {
    const float* source = (const float*)d_in[0];
    const float* target = (const float*)d_in[1];
    const float* W_src  = (const float*)d_in[2];
    const float* b_src  = (const float*)d_in[3];
    const float* W_tgt  = (const float*)d_in[4];
    const float* b_tgt  = (const float*)d_in[5];
    const float* W_res  = (const float*)d_in[6];
    const float* b_res  = (const float*)d_in[7];
    const float* W_prob = (const float*)d_in[8];
    const float* b_prob = (const float*)d_in[9];
    float* out = (float*)d_out;

    unsigned short* abf = (unsigned short*)d_ws;        // 4096*256 bf16 = 2 MB
    unsigned short* wtb = abf + 2 * NSRC * D_;          // 2*256*256 bf16 = 256 KB

    prep_kernel<<<1568, 256, 0, stream>>>(source, target, W_src, W_tgt,
                                          W_prob, b_prob, abf, wtb, out);
    mega_kernel<<<dim3(8, 8, 4), 512, 0, stream>>>(abf, wtb, b_src, b_tgt,
                                                   W_res, b_res, out);
}

// Round 9
// 114.313 us; speedup vs baseline: 1.2199x; 1.0037x over previous
//
#include <hip/hip_runtime.h>

#define B_ 4
#define S_ 512
#define T_ 512
#define D_ 256
#define NSRC (B_ * S_)            // 2048 source rows
#define K2F 2.8853900817779268f   // 2*log2(e): exp2(x*K2F) = e^(2x)

typedef __attribute__((ext_vector_type(8))) short short8;   // 8 bf16
typedef __attribute__((ext_vector_type(4))) float f32x4;
typedef __attribute__((ext_vector_type(2))) float f32x2;

__device__ __forceinline__ unsigned short f2bf(float f) {
    union { float f; unsigned u; } v; v.f = f;
    unsigned r = v.u + 0x7FFF + ((v.u >> 16) & 1);   // RNE
    return (unsigned short)(r >> 16);
}

// ---------------------------------------------------------------------------
// K1: prep (validated R3). blocks 0..1023: cast [src;tgt] -> abf bf16.
//     blocks 1024..1055: W -> WT bf16 via LDS 64x64 tile transpose.
//     blocks 1056..1567: prob = softmax(target @ W_prob + b_prob).
// ---------------------------------------------------------------------------
__global__ __launch_bounds__(256) void prep_kernel(
    const float* __restrict__ src, const float* __restrict__ tgt,
    const float* __restrict__ Wsrc, const float* __restrict__ Wtgt,
    const float* __restrict__ Wp, const float* __restrict__ bp,
    unsigned short* __restrict__ abf, unsigned short* __restrict__ wtb,
    float* __restrict__ out)
{
    __shared__ float tl[64 * 65];
    const int blk = blockIdx.x, tid = threadIdx.x;

    if (blk < 1024) {
        int i4 = blk * 256 + tid;
        const int half = NSRC * D_ / 4;
        const float4* in = (i4 < half) ? (const float4*)src : (const float4*)tgt;
        int j = (i4 < half) ? i4 : i4 - half;
        float4 v = in[j];
        ushort4 o;
        o.x = f2bf(v.x); o.y = f2bf(v.y); o.z = f2bf(v.z); o.w = f2bf(v.w);
        *(ushort4*)&abf[i4 * 4] = o;
    } else if (blk < 1056) {
        int wb = blk - 1024;
        int e = wb >> 4, ti = wb & 15, tr = ti >> 2, tc = ti & 3;
        int r0 = tr * 64, c0 = tc * 64;
        const float* W = e ? Wtgt : Wsrc;
        #pragma unroll
        for (int it = 0; it < 4; it++) {
            int rr = (tid >> 4) + it * 16;
            int cc = (tid & 15) * 4;
            float4 v = *(const float4*)&W[(r0 + rr) * D_ + c0 + cc];
            tl[(cc + 0) * 65 + rr] = v.x;
            tl[(cc + 1) * 65 + rr] = v.y;
            tl[(cc + 2) * 65 + rr] = v.z;
            tl[(cc + 3) * 65 + rr] = v.w;
        }
        __syncthreads();
        #pragma unroll
        for (int it = 0; it < 2; it++) {
            int jj = (tid >> 3) + it * 32;
            int kk = (tid & 7) * 8;
            ushort4 lo, hi;
            lo.x = f2bf(tl[jj * 65 + kk + 0]); lo.y = f2bf(tl[jj * 65 + kk + 1]);
            lo.z = f2bf(tl[jj * 65 + kk + 2]); lo.w = f2bf(tl[jj * 65 + kk + 3]);
            hi.x = f2bf(tl[jj * 65 + kk + 4]); hi.y = f2bf(tl[jj * 65 + kk + 5]);
            hi.z = f2bf(tl[jj * 65 + kk + 6]); hi.w = f2bf(tl[jj * 65 + kk + 7]);
            int idx = (e * 256 + c0 + jj) * D_ + r0 + kk;
            *(ushort4*)&wtb[idx] = lo;
            *(ushort4*)&wtb[idx + 4] = hi;
        }
    } else {
        int row  = (blk - 1056) * 4 + (tid >> 6);
        int lane = tid & 63;
        float p0 = 0.f, p1 = 0.f;
        #pragma unroll
        for (int i = 0; i < 4; i++) {
            int d = lane + i * 64;
            float v = tgt[row * D_ + d];
            float2 w = *(const float2*)&Wp[d * 2];
            p0 = fmaf(v, w.x, p0);
            p1 = fmaf(v, w.y, p1);
        }
        #pragma unroll
        for (int off = 32; off > 0; off >>= 1) {
            p0 += __shfl_down(p0, off, 64);
            p1 += __shfl_down(p1, off, 64);
        }
        if (lane == 0) {
            const float L2E = 1.4426950408889634f;
            float l0 = p0 + bp[0], l1 = p1 + bp[1];
            float e10 = __builtin_amdgcn_exp2f((l1 - l0) * L2E);
            float e01 = __builtin_amdgcn_exp2f((l0 - l1) * L2E);
            out[B_ * T_ * S_ + row * 2 + 0] = __builtin_amdgcn_rcpf(1.f + e10);
            out[B_ * T_ * S_ + row * 2 + 1] = __builtin_amdgcn_rcpf(1.f + e01);
        }
    }
}

// ---------------------------------------------------------------------------
// K2: mega v7 — 768 threads = 12 waves = 3/SIMD: 1 producer + 2 consumers.
// Grid (8,8,4) = 256 blocks = 1 block/CU. Tile 64s x 64t, D in 4 chunks.
// Producers (waves 0-3): phase A (MFMA lin + exp2) into double-buffered LDS;
//   wave pw: mat=pw>>1, rowgroups 2*(pw&1)+{0,1}, af[2][8] resident.
// Consumers (waves 4-11): phase B, 4s x 2t per thread (8 outputs/lane), k+1
//   register prefetch; two consumer waves per SIMD interleave in HW to hide
//   rcp-chain + ds_read latency. Wres via scalar loads.
// genP = C0 - 2 * sum_d w_d / (1 + ys*yt),  C0 = sum w + b_res.
// ---------------------------------------------------------------------------
#define LSTR 68
__global__ __launch_bounds__(768, 1) void mega_kernel(
    const unsigned short* __restrict__ abf, const unsigned short* __restrict__ wtb,
    const float* __restrict__ bsrc, const float* __restrict__ btgt,
    const float* __restrict__ Wres, const float* __restrict__ bres,
    float* __restrict__ out)
{
    __shared__ float ls[2][64 * LSTR];   // [buf][d][s]
    __shared__ float lt[2][64 * LSTR];   // [buf][d][t]
    __shared__ float c0s;

    const int tid = threadIdx.x;
    const int lane = tid & 63, w = tid >> 6;
    const int s0 = blockIdx.x * 64;
    const int t0 = blockIdx.y * 64;
    const int b  = blockIdx.z;

    if (w == 0) {
        float s = Wres[lane] + Wres[lane + 64] + Wres[lane + 128] + Wres[lane + 192];
        #pragma unroll
        for (int off = 32; off > 0; off >>= 1) s += __shfl_xor(s, off, 64);
        if (lane == 0) c0s = s + bres[0];
    }

    const bool producer = (w < 4);

    // ---- producer state ----
    const int pw  = w & 3;
    const int mat = pw >> 1;             // 0 = s-mat, 1 = t-mat
    const int rb  = 2 * (pw & 1);        // rowgroup base
    const int n = lane & 15, quad = lane >> 4;
    const float* bias = mat ? btgt : bsrc;
    const unsigned short* wtbase = wtb + mat * 256 * D_;
    const int R0 = mat ? (NSRC + b * T_ + t0) : (b * S_ + s0);

    short8 af[2][8];
    if (producer) {
        #pragma unroll
        for (int rg = 0; rg < 2; rg++)
            #pragma unroll
            for (int ks = 0; ks < 8; ks++)
                af[rg][ks] = *(const short8*)&abf[(R0 + (rb + rg) * 16 + n) * D_ + ks * 32 + quad * 8];
    }

    auto phaseA = [&](int c, int bi) {
        float* lx = (mat ? lt[bi] : ls[bi]);
        #pragma unroll
        for (int cg = 0; cg < 4; cg++) {
            const int gcol = c * 4 + cg;
            const unsigned short* bptr = &wtbase[(gcol * 16 + n) * D_ + quad * 8];
            short8 bf[8];
            #pragma unroll
            for (int ks = 0; ks < 8; ks++) bf[ks] = *(const short8*)&bptr[ks * 32];
            const int dloc = cg * 16 + n;
            const float bv = bias[gcol * 16 + n];
            #pragma unroll
            for (int rg = 0; rg < 2; rg++) {
                f32x4 a4 = {0.f, 0.f, 0.f, 0.f};
                #pragma unroll
                for (int ks = 0; ks < 8; ks++)
                    a4 = __builtin_amdgcn_mfma_f32_16x16x32_bf16(af[rg][ks], bf[ks], a4, 0, 0, 0);
                float4 o;
                o.x = __builtin_amdgcn_exp2f((a4[0] + bv) * K2F);
                o.y = __builtin_amdgcn_exp2f((a4[1] + bv) * K2F);
                o.z = __builtin_amdgcn_exp2f((a4[2] + bv) * K2F);
                o.w = __builtin_amdgcn_exp2f((a4[3] + bv) * K2F);
                *(float4*)&lx[dloc * LSTR + (rb + rg) * 16 + quad * 4] = o;
            }
        }
    };

    // ---- consumer state ----
    const int cl = tid - 256;            // 0..511
    const int m = cl & 15;               // s = s0 + 4m..4m+3
    const int g = cl >> 4;               // t = t0 + 2g, 2g+1   (0..31)
    f32x2 acc[2][2];
    #pragma unroll
    for (int i = 0; i < 2; i++) {
        acc[i][0] = (f32x2){0.f, 0.f};
        acc[i][1] = (f32x2){0.f, 0.f};
    }

    if (producer) phaseA(0, 0);
    __syncthreads();

    for (int c = 0; c < 4; c++) {
        const int bi = c & 1;
        if (producer) {
            if (c < 3) phaseA(c + 1, bi ^ 1);
        } else {
            const float* lsb = ls[bi];
            const float* ltb = lt[bi];
            const float* wp = &Wres[c * 64];
            float4 av = *(const float4*)&lsb[4 * m];
            float2 cv = *(const float2*)&ltb[2 * g];
            #pragma unroll 8
            for (int k = 0; k < 64; k++) {
                float4 avn = av; float2 cvn = cv;
                if (k < 63) {
                    avn = *(const float4*)&lsb[(k + 1) * LSTR + 4 * m];
                    cvn = *(const float2*)&ltb[(k + 1) * LSTR + 2 * g];
                }
                const float wv = wp[k];              // uniform -> s_load
                const f32x2 w2 = {wv, wv};
                f32x2 r;
                r.x = __builtin_amdgcn_rcpf(fmaf(cv.x, av.x, 1.f));
                r.y = __builtin_amdgcn_rcpf(fmaf(cv.x, av.y, 1.f));
                acc[0][0] = r * w2 + acc[0][0];
                r.x = __builtin_amdgcn_rcpf(fmaf(cv.x, av.z, 1.f));
                r.y = __builtin_amdgcn_rcpf(fmaf(cv.x, av.w, 1.f));
                acc[0][1] = r * w2 + acc[0][1];
                r.x = __builtin_amdgcn_rcpf(fmaf(cv.y, av.x, 1.f));
                r.y = __builtin_amdgcn_rcpf(fmaf(cv.y, av.y, 1.f));
                acc[1][0] = r * w2 + acc[1][0];
                r.x = __builtin_amdgcn_rcpf(fmaf(cv.y, av.z, 1.f));
                r.y = __builtin_amdgcn_rcpf(fmaf(cv.y, av.w, 1.f));
                acc[1][1] = r * w2 + acc[1][1];
                av = avn; cv = cvn;
            }
        }
        __syncthreads();
    }

    if (!producer) {
        const float C0 = c0s;
        #pragma unroll
        for (int i = 0; i < 2; i++) {
            float4 o;
            o.x = C0 - 2.f * acc[i][0].x;
            o.y = C0 - 2.f * acc[i][0].y;
            o.z = C0 - 2.f * acc[i][1].x;
            o.w = C0 - 2.f * acc[i][1].y;
            *(float4*)&out[(b * T_ + t0 + 2 * g + i) * S_ + s0 + 4 * m] = o;
        }
    }
}

extern "C" void kernel_launch(void* const* d_in, const int* in_sizes, int n_in,
                              void* d_out, int out_size, void* d_ws, size_t ws_size,
                              hipStream_t stream) {
    const float* source = (const float*)d_in[0];
    const float* target = (const float*)d_in[1];
    const float* W_src  = (const float*)d_in[2];
    const float* b_src  = (const float*)d_in[3];
    const float* W_tgt  = (const float*)d_in[4];
    const float* b_tgt  = (const float*)d_in[5];
    const float* W_res  = (const float*)d_in[6];
    const float* b_res  = (const float*)d_in[7];
    const float* W_prob = (const float*)d_in[8];
    const float* b_prob = (const float*)d_in[9];
    float* out = (float*)d_out;

    unsigned short* abf = (unsigned short*)d_ws;        // 4096*256 bf16 = 2 MB
    unsigned short* wtb = abf + 2 * NSRC * D_;          // 2*256*256 bf16 = 256 KB

    prep_kernel<<<1568, 256, 0, stream>>>(source, target, W_src, W_tgt,
                                          W_prob, b_prob, abf, wtb, out);
    mega_kernel<<<dim3(8, 8, 4), 768, 0, stream>>>(abf, wtb, b_src, b_tgt,
                                                   W_res, b_res, out);
}

// Round 10
// 110.831 us; speedup vs baseline: 1.2582x; 1.0314x over previous
//
#include <hip/hip_runtime.h>

#define B_ 4
#define S_ 512
#define T_ 512
#define D_ 256
#define NSRC (B_ * S_)            // 2048 source rows
#define K2F 2.8853900817779268f   // 2*log2(e): exp2(x*K2F) = e^(2x)

typedef __attribute__((ext_vector_type(8))) short short8;   // 8 bf16
typedef __attribute__((ext_vector_type(4))) float f32x4;
typedef __attribute__((ext_vector_type(2))) float f32x2;

__device__ __forceinline__ unsigned short f2bf(float f) {
    union { float f; unsigned u; } v; v.f = f;
    unsigned r = v.u + 0x7FFF + ((v.u >> 16) & 1);   // RNE
    return (unsigned short)(r >> 16);
}

// ---------------------------------------------------------------------------
// K1: prep (validated R3). blocks 0..1023: cast [src;tgt] -> abf bf16.
//     blocks 1024..1055: W -> WT bf16 via LDS 64x64 tile transpose.
//     blocks 1056..1567: prob = softmax(target @ W_prob + b_prob).
// ---------------------------------------------------------------------------
__global__ __launch_bounds__(256) void prep_kernel(
    const float* __restrict__ src, const float* __restrict__ tgt,
    const float* __restrict__ Wsrc, const float* __restrict__ Wtgt,
    const float* __restrict__ Wp, const float* __restrict__ bp,
    unsigned short* __restrict__ abf, unsigned short* __restrict__ wtb,
    float* __restrict__ out)
{
    __shared__ float tl[64 * 65];
    const int blk = blockIdx.x, tid = threadIdx.x;

    if (blk < 1024) {
        int i4 = blk * 256 + tid;
        const int half = NSRC * D_ / 4;
        const float4* in = (i4 < half) ? (const float4*)src : (const float4*)tgt;
        int j = (i4 < half) ? i4 : i4 - half;
        float4 v = in[j];
        ushort4 o;
        o.x = f2bf(v.x); o.y = f2bf(v.y); o.z = f2bf(v.z); o.w = f2bf(v.w);
        *(ushort4*)&abf[i4 * 4] = o;
    } else if (blk < 1056) {
        int wb = blk - 1024;
        int e = wb >> 4, ti = wb & 15, tr = ti >> 2, tc = ti & 3;
        int r0 = tr * 64, c0 = tc * 64;
        const float* W = e ? Wtgt : Wsrc;
        #pragma unroll
        for (int it = 0; it < 4; it++) {
            int rr = (tid >> 4) + it * 16;
            int cc = (tid & 15) * 4;
            float4 v = *(const float4*)&W[(r0 + rr) * D_ + c0 + cc];
            tl[(cc + 0) * 65 + rr] = v.x;
            tl[(cc + 1) * 65 + rr] = v.y;
            tl[(cc + 2) * 65 + rr] = v.z;
            tl[(cc + 3) * 65 + rr] = v.w;
        }
        __syncthreads();
        #pragma unroll
        for (int it = 0; it < 2; it++) {
            int jj = (tid >> 3) + it * 32;
            int kk = (tid & 7) * 8;
            ushort4 lo, hi;
            lo.x = f2bf(tl[jj * 65 + kk + 0]); lo.y = f2bf(tl[jj * 65 + kk + 1]);
            lo.z = f2bf(tl[jj * 65 + kk + 2]); lo.w = f2bf(tl[jj * 65 + kk + 3]);
            hi.x = f2bf(tl[jj * 65 + kk + 4]); hi.y = f2bf(tl[jj * 65 + kk + 5]);
            hi.z = f2bf(tl[jj * 65 + kk + 6]); hi.w = f2bf(tl[jj * 65 + kk + 7]);
            int idx = (e * 256 + c0 + jj) * D_ + r0 + kk;
            *(ushort4*)&wtb[idx] = lo;
            *(ushort4*)&wtb[idx + 4] = hi;
        }
    } else {
        int row  = (blk - 1056) * 4 + (tid >> 6);
        int lane = tid & 63;
        float p0 = 0.f, p1 = 0.f;
        #pragma unroll
        for (int i = 0; i < 4; i++) {
            int d = lane + i * 64;
            float v = tgt[row * D_ + d];
            float2 w = *(const float2*)&Wp[d * 2];
            p0 = fmaf(v, w.x, p0);
            p1 = fmaf(v, w.y, p1);
        }
        #pragma unroll
        for (int off = 32; off > 0; off >>= 1) {
            p0 += __shfl_down(p0, off, 64);
            p1 += __shfl_down(p1, off, 64);
        }
        if (lane == 0) {
            const float L2E = 1.4426950408889634f;
            float l0 = p0 + bp[0], l1 = p1 + bp[1];
            float e10 = __builtin_amdgcn_exp2f((l1 - l0) * L2E);
            float e01 = __builtin_amdgcn_exp2f((l0 - l1) * L2E);
            out[B_ * T_ * S_ + row * 2 + 0] = __builtin_amdgcn_rcpf(1.f + e10);
            out[B_ * T_ * S_ + row * 2 + 1] = __builtin_amdgcn_rcpf(1.f + e01);
        }
    }
}

// ---------------------------------------------------------------------------
// K2: mega v8 — producer/consumer waves + d-pair rcp folding + packed fp32.
// 768 threads = 12 waves = 3/SIMD (1 producer + 2 consumers per SIMD),
// grid (8,8,4) = 256 blocks = 1/CU. Tile 64s x 64t, D in 4 chunks (dbuf LDS).
// Consumers fold two d-terms into ONE rcp:
//   w0/(1+y0) + w1/(1+y1) = [w0(1+y1)+w1(1+y0)] / [(1+y0)(1+y1)]
// and do all full-rate math as f32x2 (v_pk_fma_f32 / v_pk_mul_f32), shifting
// the bottleneck off the quarter-rate trans pipe onto the packed VALU pipe.
// genP = C0 - 2 * sum_d w_d / (1 + ys*yt),  C0 = sum w + b_res.
// ---------------------------------------------------------------------------
#define LSTR 68
__global__ __launch_bounds__(768, 1) void mega_kernel(
    const unsigned short* __restrict__ abf, const unsigned short* __restrict__ wtb,
    const float* __restrict__ bsrc, const float* __restrict__ btgt,
    const float* __restrict__ Wres, const float* __restrict__ bres,
    float* __restrict__ out)
{
    __shared__ float ls[2][64 * LSTR];   // [buf][d][s]
    __shared__ float lt[2][64 * LSTR];   // [buf][d][t]
    __shared__ float c0s;

    const int tid = threadIdx.x;
    const int lane = tid & 63, w = tid >> 6;
    const int s0 = blockIdx.x * 64;
    const int t0 = blockIdx.y * 64;
    const int b  = blockIdx.z;

    if (w == 0) {
        float s = Wres[lane] + Wres[lane + 64] + Wres[lane + 128] + Wres[lane + 192];
        #pragma unroll
        for (int off = 32; off > 0; off >>= 1) s += __shfl_xor(s, off, 64);
        if (lane == 0) c0s = s + bres[0];
    }

    const bool producer = (w < 4);

    // ---- producer state ----
    const int pw  = w & 3;
    const int mat = pw >> 1;             // 0 = s-mat, 1 = t-mat
    const int rb  = 2 * (pw & 1);        // rowgroup base
    const int n = lane & 15, quad = lane >> 4;
    const float* bias = mat ? btgt : bsrc;
    const unsigned short* wtbase = wtb + mat * 256 * D_;
    const int R0 = mat ? (NSRC + b * T_ + t0) : (b * S_ + s0);

    short8 af[2][8];
    if (producer) {
        #pragma unroll
        for (int rg = 0; rg < 2; rg++)
            #pragma unroll
            for (int ks = 0; ks < 8; ks++)
                af[rg][ks] = *(const short8*)&abf[(R0 + (rb + rg) * 16 + n) * D_ + ks * 32 + quad * 8];
    }

    auto phaseA = [&](int c, int bi) {
        float* lx = (mat ? lt[bi] : ls[bi]);
        #pragma unroll
        for (int cg = 0; cg < 4; cg++) {
            const int gcol = c * 4 + cg;
            const unsigned short* bptr = &wtbase[(gcol * 16 + n) * D_ + quad * 8];
            short8 bf[8];
            #pragma unroll
            for (int ks = 0; ks < 8; ks++) bf[ks] = *(const short8*)&bptr[ks * 32];
            const int dloc = cg * 16 + n;
            const float bv = bias[gcol * 16 + n];
            #pragma unroll
            for (int rg = 0; rg < 2; rg++) {
                f32x4 a4 = {0.f, 0.f, 0.f, 0.f};
                #pragma unroll
                for (int ks = 0; ks < 8; ks++)
                    a4 = __builtin_amdgcn_mfma_f32_16x16x32_bf16(af[rg][ks], bf[ks], a4, 0, 0, 0);
                float4 o;
                o.x = __builtin_amdgcn_exp2f((a4[0] + bv) * K2F);
                o.y = __builtin_amdgcn_exp2f((a4[1] + bv) * K2F);
                o.z = __builtin_amdgcn_exp2f((a4[2] + bv) * K2F);
                o.w = __builtin_amdgcn_exp2f((a4[3] + bv) * K2F);
                *(float4*)&lx[dloc * LSTR + (rb + rg) * 16 + quad * 4] = o;
            }
        }
    };

    // ---- consumer state ----
    const int cl = tid - 256;            // 0..511
    const int m = cl & 15;               // s = s0 + 4m..4m+3
    const int g = cl >> 4;               // t = t0 + 2g, 2g+1   (0..31)
    f32x2 acc[2][2];                     // [t-idx i][s-pair jp]
    #pragma unroll
    for (int i = 0; i < 2; i++) {
        acc[i][0] = (f32x2){0.f, 0.f};
        acc[i][1] = (f32x2){0.f, 0.f};
    }

    if (producer) phaseA(0, 0);
    __syncthreads();

    for (int c = 0; c < 4; c++) {
        const int bi = c & 1;
        if (producer) {
            if (c < 3) phaseA(c + 1, bi ^ 1);
        } else {
            const float* lsb = ls[bi];
            const float* ltb = lt[bi];
            const float* wp = &Wres[c * 64];
            const f32x2 one2 = {1.f, 1.f};
            #pragma unroll 8
            for (int kp = 0; kp < 32; kp++) {
                const int d0 = 2 * kp, d1 = 2 * kp + 1;
                float4 av0 = *(const float4*)&lsb[d0 * LSTR + 4 * m];
                float4 av1 = *(const float4*)&lsb[d1 * LSTR + 4 * m];
                float2 cv0 = *(const float2*)&ltb[d0 * LSTR + 2 * g];
                float2 cv1 = *(const float2*)&ltb[d1 * LSTR + 2 * g];
                const float w0 = wp[d0], w1 = wp[d1];        // uniform -> s_load
                const f32x2 w0v = {w0, w0}, w1v = {w1, w1};
                f32x2 a0p[2] = {{av0.x, av0.y}, {av0.z, av0.w}};
                f32x2 a1p[2] = {{av1.x, av1.y}, {av1.z, av1.w}};
                const float cc0[2] = {cv0.x, cv0.y};
                const float cc1[2] = {cv1.x, cv1.y};
                #pragma unroll
                for (int i = 0; i < 2; i++) {
                    const f32x2 c0v = {cc0[i], cc0[i]};
                    const f32x2 c1v = {cc1[i], cc1[i]};
                    #pragma unroll
                    for (int jp = 0; jp < 2; jp++) {
                        f32x2 dd0 = a0p[jp] * c0v + one2;    // pk_fma: 1+y0
                        f32x2 dd1 = a1p[jp] * c1v + one2;    // pk_fma: 1+y1
                        f32x2 den = dd0 * dd1;               // pk_mul
                        f32x2 tnu = dd0 * w1v;               // pk_mul
                        f32x2 num = dd1 * w0v + tnu;         // pk_fma
                        f32x2 r;
                        r.x = __builtin_amdgcn_rcpf(den.x);
                        r.y = __builtin_amdgcn_rcpf(den.y);
                        acc[i][jp] = num * r + acc[i][jp];   // pk_fma
                    }
                }
            }
        }
        __syncthreads();
    }

    if (!producer) {
        const float C0 = c0s;
        #pragma unroll
        for (int i = 0; i < 2; i++) {
            float4 o;
            o.x = C0 - 2.f * acc[i][0].x;
            o.y = C0 - 2.f * acc[i][0].y;
            o.z = C0 - 2.f * acc[i][1].x;
            o.w = C0 - 2.f * acc[i][1].y;
            *(float4*)&out[(b * T_ + t0 + 2 * g + i) * S_ + s0 + 4 * m] = o;
        }
    }
}

extern "C" void kernel_launch(void* const* d_in, const int* in_sizes, int n_in,
                              void* d_out, int out_size, void* d_ws, size_t ws_size,
                              hipStream_t stream) {
    const float* source = (const float*)d_in[0];
    const float* target = (const float*)d_in[1];
    const float* W_src  = (const float*)d_in[2];
    const float* b_src  = (const float*)d_in[3];
    const float* W_tgt  = (const float*)d_in[4];
    const float* b_tgt  = (const float*)d_in[5];
    const float* W_res  = (const float*)d_in[6];
    const float* b_res  = (const float*)d_in[7];
    const float* W_prob = (const float*)d_in[8];
    const float* b_prob = (const float*)d_in[9];
    float* out = (float*)d_out;

    unsigned short* abf = (unsigned short*)d_ws;        // 4096*256 bf16 = 2 MB
    unsigned short* wtb = abf + 2 * NSRC * D_;          // 2*256*256 bf16 = 256 KB

    prep_kernel<<<1568, 256, 0, stream>>>(source, target, W_src, W_tgt,
                                          W_prob, b_prob, abf, wtb, out);
    mega_kernel<<<dim3(8, 8, 4), 768, 0, stream>>>(abf, wtb, b_src, b_tgt,
                                                   W_res, b_res, out);
}